// Round 3
// baseline (154.867 us; speedup 1.0000x reference)
//
#include <hip/hip_runtime.h>
#include <stdint.h>

#define NB 8
#define CIN 64
#define COUT 64
#define HH 128
#define WW 128

typedef unsigned short ushort_t;
typedef unsigned int uint_t;
typedef __attribute__((ext_vector_type(8))) __bf16 bf16x8;
typedef __attribute__((ext_vector_type(4))) float f32x4;

__device__ __forceinline__ ushort_t f2bf(float f) {
  uint_t u = __builtin_bit_cast(uint_t, f);
  u += 0x7fffu + ((u >> 16) & 1u);
  return (ushort_t)(u >> 16);
}

// workspace layout (bytes)
#define WS_A    0                 // 8*64*576 bf16 = 589824 B
#define WS_XSUM 589824            // 512 floats

// Per-(b,c) spatial sum of x: 512 blocks, contiguous float4 reads (L3-hot after restore).
__global__ void k_mean(const float* __restrict__ x, float* __restrict__ xsum) {
  __shared__ float red[256];
  int bc = blockIdx.x;  // b*64+c
  int tid = threadIdx.x;
  const float4* xp4 = (const float4*)(x + (size_t)bc * 16384);
  float s = 0.f;
#pragma unroll
  for (int i = 0; i < 16; ++i) {
    float4 v = xp4[tid + i * 256];
    s += (v.x + v.y) + (v.z + v.w);
  }
  red[tid] = s;
  __syncthreads();
  for (int st = 128; st > 0; st >>= 1) {
    if (tid < st) red[tid] += red[tid + st];
    __syncthreads();
  }
  if (tid == 0) xsum[bc] = red[0];
}

// Per (b,o): ctx_vec -> kernels (tanh, mean-subtract) -> fold value_w -> A[b][o][tap*64+c] bf16
__global__ void k_gen(const float* __restrict__ xsum,
                      const float* __restrict__ ctx_w, const float* __restrict__ ctx_b,
                      const float* __restrict__ kg_w, const float* __restrict__ kg_b,
                      const float* __restrict__ gamma, const float* __restrict__ value_w,
                      ushort_t* __restrict__ A) {
  __shared__ float xm[64];
  __shared__ float ctxv[16];
  __shared__ float ks_[576];
  __shared__ float red[256];
  __shared__ float vw[4096];
  int b = blockIdx.x >> 6;
  int o = blockIdx.x & 63;
  int tid = threadIdx.x;
  if (tid < 64) xm[tid] = xsum[b * 64 + tid] * (1.f / 16384.f);
#pragma unroll
  for (int p = 0; p < 16; ++p) vw[tid + p * 256] = value_w[tid + p * 256];
  __syncthreads();
  if (tid < 16) {
    float s = ctx_b[tid];
#pragma unroll 8
    for (int c = 0; c < 64; ++c) s += xm[c] * ctx_w[tid * 64 + c];
    ctxv[tid] = s;
  }
  __syncthreads();
  float val[3] = {0.f, 0.f, 0.f};
  float partial = 0.f;
#pragma unroll
  for (int p = 0; p < 3; ++p) {
    int i = tid + p * 256;
    if (i < 576) {
      int n = o * 576 + i;  // kernels_flat index: o*(C*K*K) + c'*9 + tap
      float s = kg_b[n];
      const float* kwp = kg_w + (size_t)n * 16;
#pragma unroll
      for (int j = 0; j < 16; ++j) s += ctxv[j] * kwp[j];
      val[p] = tanhf(s);
      partial += val[p];
    }
  }
  red[tid] = partial;
  __syncthreads();
  for (int s = 128; s > 0; s >>= 1) {
    if (tid < s) red[tid] += red[tid + s];
    __syncthreads();
  }
  float mean = red[0] * (1.f / 576.f);
  float lam = 1.f / (1.f + expf(-gamma[o]));
#pragma unroll
  for (int p = 0; p < 3; ++p) {
    int i = tid + p * 256;
    if (i < 576) ks_[i] = val[p] - lam * mean;  // i = c'*9 + tap
  }
  __syncthreads();
  ushort_t* Ao = A + (size_t)(b * 64 + o) * 576;
#pragma unroll
  for (int p = 0; p < 3; ++p) {
    int f = tid + p * 256;
    if (f < 576) {
      int tap = f >> 6;  // f = tap*64 + c
      int c = f & 63;
      float s = 0.f;
#pragma unroll 8
      for (int cp = 0; cp < 64; ++cp) s += ks_[cp * 9 + tap] * vw[cp * 64 + c];
      Ao[f] = f2bf(s);
    }
  }
}

// Dynamic 3x3 conv via MFMA, staging DIRECTLY from x (B,C,H,W) f32 with inline bf16
// conversion (no transpose kernel / no xT round-trip). Block = batch x (4x32) px tile.
// Wave = 32 o x 64 px: each B-fragment LDS read feeds two MFMAs.
__launch_bounds__(256, 2)
__global__ void k_conv(const float* __restrict__ x, const ushort_t* __restrict__ A,
                       const float* __restrict__ bias, float* __restrict__ out) {
  // LDS x tile: [6 rows][34 cols][72 ch-padded] bf16 (row stride 144 B, 16B-aligned)
  __shared__ __align__(16) ushort_t xs[6 * 34 * 72];
  int bx = blockIdx.x;
  int b = bx >> 7;
  int rem = bx & 127;
  int h0 = (rem >> 2) * 4;
  int w0 = (rem & 3) * 32;
  int tid = threadIdx.x;
  int wave = tid >> 6;
  int lane = tid & 63;
  int n16 = lane & 15;
  int q = lane >> 4;
  int p  = wave & 1;   // pixel half
  int oh = wave >> 1;  // o half

  // A fragments for both 16-o tiles: A[m=lane&15][k=q*8+j], f = tap*64 + c
  bf16x8 af[2][18];
#pragma unroll
  for (int t = 0; t < 2; ++t) {
    const ushort_t* Ag = A + (size_t)(b * 64 + oh * 32 + t * 16 + n16) * 576 + q * 8;
#pragma unroll
    for (int ks = 0; ks < 18; ++ks)
      af[t][ks] = *reinterpret_cast<const bf16x8*>(Ag + ks * 32);
  }

  // ---- stage x tile from native (C,H,W) f32, channel-pairs -> packed bf16x2 ----
  const float* xb = x + (size_t)b * 64 * 16384;
  // main body: 6 lr x 32 cp x 32 lc' = 6144 = 24*256 chunks, w always in-bounds
#pragma unroll
  for (int it = 0; it < 24; ++it) {
    int chunk = tid + it * 256;
    int lcp = chunk & 31;          // w = w0 + lcp, lds col = lcp+1
    int cp  = (chunk >> 5) & 31;   // channel pair
    int lr  = chunk >> 10;         // 0..5
    int hh = h0 - 1 + lr;
    int ww = w0 + lcp;
    uint_t pk = 0;
    if (hh >= 0 && hh < 128) {
      const float* src = xb + ((size_t)(2 * cp) * 128 + hh) * 128 + ww;
      float f0 = src[0];
      float f1 = src[16384];
      pk = (uint_t)f2bf(f0) | ((uint_t)f2bf(f1) << 16);
    }
    *reinterpret_cast<uint_t*>(xs + (lr * 34 + (lcp + 1)) * 72 + 2 * cp) = pk;
  }
  // halo cols (lc=0 -> w0-1, lc=33 -> w0+32): 2 x 6 x 32 = 384 chunks
  {
    int chunk = tid + ((tid < 128) ? 256 : 0);  // threads 0..255 cover 0..255 & 256..383
    // two passes folded: first handle chunk=tid (<256), then tid<128 handles 256..383
    // do explicitly:
  }
#pragma unroll
  for (int it = 0; it < 2; ++it) {
    int chunk = tid + it * 256;
    if (chunk < 384) {
      int side = chunk & 1;
      int rest = chunk >> 1;       // 0..191
      int cp = rest & 31;
      int lr = rest >> 5;          // 0..5
      int lc = side ? 33 : 0;
      int hh = h0 - 1 + lr;
      int ww = w0 - 1 + lc;        // w0-1 or w0+32
      uint_t pk = 0;
      if (hh >= 0 && hh < 128 && ww >= 0 && ww < 128) {
        const float* src = xb + ((size_t)(2 * cp) * 128 + hh) * 128 + ww;
        float f0 = src[0];
        float f1 = src[16384];
        pk = (uint_t)f2bf(f0) | ((uint_t)f2bf(f1) << 16);
      }
      *reinterpret_cast<uint_t*>(xs + (lr * 34 + lc) * 72 + 2 * cp) = pk;
    }
  }
  __syncthreads();

  f32x4 acc[4][2];
#pragma unroll
  for (int i = 0; i < 4; ++i)
#pragma unroll
    for (int t = 0; t < 2; ++t) acc[i][t] = (f32x4){0.f, 0.f, 0.f, 0.f};

  const ushort_t* xsl = xs + n16 * 72 + q * 8;
#pragma unroll
  for (int pt = 0; pt < 4; ++pt) {
    int nt = p * 4 + pt;
    int rr = nt >> 1, cb = nt & 1;
#pragma unroll
    for (int tap = 0; tap < 9; ++tap) {
      int kh = tap / 3, kw2 = tap % 3;
#pragma unroll
      for (int cq = 0; cq < 2; ++cq) {
        bf16x8 bf = *reinterpret_cast<const bf16x8*>(
            xsl + ((rr + kh) * 34 + cb * 16 + kw2) * 72 + cq * 32);
        int ks = tap * 2 + cq;
        acc[pt][0] = __builtin_amdgcn_mfma_f32_16x16x32_bf16(af[0][ks], bf, acc[pt][0], 0, 0, 0);
        acc[pt][1] = __builtin_amdgcn_mfma_f32_16x16x32_bf16(af[1][ks], bf, acc[pt][1], 0, 0, 0);
      }
    }
  }

  // epilogue: D mapping col(pixel)=lane&15, row(o)=q*4+reg
#pragma unroll
  for (int pt = 0; pt < 4; ++pt) {
    int nt = p * 4 + pt;
    int rr = nt >> 1, cb = nt & 1;
    int hcur = h0 + rr;
    int wcur = w0 + cb * 16 + n16;
#pragma unroll
    for (int t = 0; t < 2; ++t) {
#pragma unroll
      for (int r = 0; r < 4; ++r) {
        int o = oh * 32 + t * 16 + q * 4 + r;
        float v = acc[pt][t][r] + bias[o];
        v = fmaxf(v, 0.f);
        out[((size_t)(b * 64 + o) * 128 + hcur) * 128 + wcur] = v;
      }
    }
  }
}

extern "C" void kernel_launch(void* const* d_in, const int* in_sizes, int n_in,
                              void* d_out, int out_size, void* d_ws, size_t ws_size,
                              hipStream_t stream) {
  const float* x       = (const float*)d_in[0];
  const float* ctx_w   = (const float*)d_in[1];
  const float* ctx_b   = (const float*)d_in[2];
  const float* kg_w    = (const float*)d_in[3];
  const float* kg_b    = (const float*)d_in[4];
  const float* gamma   = (const float*)d_in[5];
  const float* bias    = (const float*)d_in[6];
  const float* value_w = (const float*)d_in[7];
  float* out = (float*)d_out;

  ushort_t* A  = (ushort_t*)((char*)d_ws + WS_A);
  float* xsum  = (float*)((char*)d_ws + WS_XSUM);

  k_mean<<<512, 256, 0, stream>>>(x, xsum);
  k_gen<<<512, 256, 0, stream>>>(xsum, ctx_w, ctx_b, kg_w, kg_b, gamma, value_w, A);
  k_conv<<<1024, 256, 0, stream>>>(x, A, bias, out);
}

// Round 4
// 130.876 us; speedup vs baseline: 1.1833x; 1.1833x over previous
//
#include <hip/hip_runtime.h>
#include <stdint.h>

#define NB 8
#define CIN 64
#define COUT 64
#define HH 128
#define WW 128

typedef unsigned short ushort_t;
typedef unsigned int uint_t;
typedef __attribute__((ext_vector_type(8))) __bf16 bf16x8;
typedef __attribute__((ext_vector_type(4))) float f32x4;

__device__ __forceinline__ ushort_t f2bf(float f) {
  uint_t u = __builtin_bit_cast(uint_t, f);
  u += 0x7fffu + ((u >> 16) & 1u);
  return (ushort_t)(u >> 16);
}

// workspace layout (bytes)
#define WS_PART 0                  // 8*128*64 f32 = 262144 B (part[b][h][c])
#define WS_XT   262144             // padded xT: 8*130*130*64 bf16 = 17305600 B
#define WS_A    17567744           // 8*64*576 bf16 = 589824 B

// Transpose x (B,C,H,W) f32 -> xTp (B,130,130,64) bf16 with zero borders;
// also write per-(b,h,c) row sums. Blocks 0..1023: (b,h). Blocks 1024..1039: zero rows 0/129.
__global__ void k_trans(const float* __restrict__ x, ushort_t* __restrict__ xTp,
                        float* __restrict__ part) {
  int bx = blockIdx.x;
  int tid = threadIdx.x;
  if (bx >= 1024) {
    int j = bx - 1024;           // 0..15
    int b = j >> 1;
    int row = (j & 1) ? 129 : 0;
    int4* dst = reinterpret_cast<int4*>(xTp + ((size_t)b * 130 + row) * 130 * 64);
    for (int it = tid; it < 1040; it += 256) dst[it] = make_int4(0, 0, 0, 0);
    return;
  }
  __shared__ float tile[64 * 129];
  int b = bx >> 7;
  int h = bx & 127;
  int w = tid & 127;
  int ch = tid >> 7;  // 0..1
  const float* xp = x + ((size_t)(b * 64) * 128 + h) * 128 + w;
#pragma unroll
  for (int p = 0; p < 32; ++p) {
    int c = p * 2 + ch;
    tile[c * 129 + w] = xp[(size_t)c * 16384];
  }
  __syncthreads();
  if (tid < 64) {
    float s = 0.f;
#pragma unroll 8
    for (int w2 = 0; w2 < 128; ++w2) s += tile[tid * 129 + w2];
    part[((size_t)b * 128 + h) * 64 + tid] = s;
  }
  // zero col 0 and col 129 of padded row h+1 (8 int4 each)
  if (tid < 16) {
    int col = (tid < 8) ? 0 : 129;
    int cc = tid & 7;
    *reinterpret_cast<int4*>(xTp + (((size_t)b * 130 + h + 1) * 130 + col) * 64 + cc * 8) =
        make_int4(0, 0, 0, 0);
  }
  ushort_t* dst = xTp + (((size_t)b * 130 + h + 1) * 130 + 1) * 64;  // col 1 = w 0
#pragma unroll
  for (int it = 0; it < 4; ++it) {
    int chunk = tid + it * 256;  // 1024 = 128 w * 8 cc
    int w2 = chunk >> 3;
    int cc = chunk & 7;
    union { ushort_t u[8]; int4 v; } pk;
#pragma unroll
    for (int j = 0; j < 8; ++j) pk.u[j] = f2bf(tile[(cc * 8 + j) * 129 + w2]);
    *reinterpret_cast<int4*>(dst + (size_t)w2 * 64 + cc * 8) = pk.v;
  }
}

// Per (b,o): reduce part -> xm; ctx_vec -> tanh kernels, mean-subtract; fold value_w
// -> A[b][o][tap*64+c] bf16
__global__ void k_gen(const float* __restrict__ part,
                      const float* __restrict__ ctx_w, const float* __restrict__ ctx_b,
                      const float* __restrict__ kg_w, const float* __restrict__ kg_b,
                      const float* __restrict__ gamma, const float* __restrict__ value_w,
                      ushort_t* __restrict__ A) {
  __shared__ float xm[64];
  __shared__ float ctxv[16];
  __shared__ float ks_[576];
  __shared__ float red[256];
  __shared__ float vw[4096];
  int b = blockIdx.x >> 6;
  int o = blockIdx.x & 63;
  int tid = threadIdx.x;
  {
    int c = tid & 63;
    int g = tid >> 6;
    float s = 0.f;
    const float* pp = part + ((size_t)b * 128 + g * 32) * 64 + c;
#pragma unroll 8
    for (int h = 0; h < 32; ++h) s += pp[h * 64];
    red[tid] = s;
  }
#pragma unroll
  for (int p = 0; p < 16; ++p) vw[tid + p * 256] = value_w[tid + p * 256];
  __syncthreads();
  if (tid < 64)
    xm[tid] = (red[tid] + red[tid + 64] + red[tid + 128] + red[tid + 192]) * (1.f / 16384.f);
  __syncthreads();
  if (tid < 16) {
    float s = ctx_b[tid];
#pragma unroll 8
    for (int c = 0; c < 64; ++c) s += xm[c] * ctx_w[tid * 64 + c];
    ctxv[tid] = s;
  }
  __syncthreads();
  float val[3] = {0.f, 0.f, 0.f};
  float partial = 0.f;
#pragma unroll
  for (int p = 0; p < 3; ++p) {
    int i = tid + p * 256;
    if (i < 576) {
      int n = o * 576 + i;  // o*(C*K*K) + c'*9 + tap
      float s = kg_b[n];
      const float* kwp = kg_w + (size_t)n * 16;
#pragma unroll
      for (int j = 0; j < 16; ++j) s += ctxv[j] * kwp[j];
      val[p] = tanhf(s);
      partial += val[p];
    }
  }
  __syncthreads();
  red[tid] = partial;
  __syncthreads();
  for (int s = 128; s > 0; s >>= 1) {
    if (tid < s) red[tid] += red[tid + s];
    __syncthreads();
  }
  float mean = red[0] * (1.f / 576.f);
  float lam = 1.f / (1.f + expf(-gamma[o]));
#pragma unroll
  for (int p = 0; p < 3; ++p) {
    int i = tid + p * 256;
    if (i < 576) ks_[i] = val[p] - lam * mean;  // i = c'*9 + tap
  }
  __syncthreads();
  ushort_t* Ao = A + (size_t)(b * 64 + o) * 576;
#pragma unroll
  for (int p = 0; p < 3; ++p) {
    int f = tid + p * 256;
    if (f < 576) {
      int tap = f >> 6;  // f = tap*64 + c
      int c = f & 63;
      float s = 0.f;
#pragma unroll 8
      for (int cp = 0; cp < 64; ++cp) s += ks_[cp * 9 + tap] * vw[cp * 64 + c];
      Ao[f] = f2bf(s);
    }
  }
}

// Dynamic 3x3 conv via MFMA from padded xTp. Block = batch x (4x32) px tile, 4 waves.
// Wave = 32 o x 64 px; A-fragments streamed per kh (48 VGPR live); B-frag LDS read
// feeds two MFMAs. Epilogue via LDS buffer -> full 128-B coalesced stores.
__launch_bounds__(256, 4)
__global__ void k_conv(const ushort_t* __restrict__ xTp, const ushort_t* __restrict__ A,
                       const float* __restrict__ bias, float* __restrict__ out) {
  __shared__ __align__(16) ushort_t xs[6 * 34 * 72];  // 29376 B
  float* buf = reinterpret_cast<float*>(xs);          // epilogue: 64*36 f32 = 9216 B

  int bx = blockIdx.x;
  int b = bx >> 7;
  int rem = bx & 127;
  int h0 = (rem >> 2) << 2;
  int w0 = (rem & 3) << 5;
  int tid = threadIdx.x;
  int lane = tid & 63;
  int wave = tid >> 6;
  int n16 = lane & 15;
  int q = lane >> 4;
  int p = wave & 1;    // pixel half (local rows 2p, 2p+1)
  int oh = wave >> 1;  // o half

  // stage x tile: padded rows h0..h0+5, padded cols w0..w0+33, 64 ch (no bounds checks)
  const ushort_t* xb = xTp + (size_t)b * (130 * 130 * 64);
#pragma unroll
  for (int it = 0; it < 7; ++it) {
    int chunk = tid + it * 256;
    if (chunk < 1632) {            // 6*34*8
      int lr = chunk / 272;
      int r2 = chunk - lr * 272;
      int lc = r2 >> 3;
      int cc = r2 & 7;
      int4 v = *reinterpret_cast<const int4*>(
          xb + ((size_t)(h0 + lr) * 130 + (w0 + lc)) * 64 + cc * 8);
      *reinterpret_cast<int4*>(xs + (lr * 34 + lc) * 72 + cc * 8) = v;
    }
  }
  __syncthreads();

  f32x4 acc[4][2];
#pragma unroll
  for (int i = 0; i < 4; ++i)
#pragma unroll
    for (int t = 0; t < 2; ++t) acc[i][t] = (f32x4){0.f, 0.f, 0.f, 0.f};

  const ushort_t* Ag0 = A + (size_t)(b * 64 + oh * 32 + n16) * 576 + q * 8;
  const ushort_t* Ag1 = Ag0 + 16 * 576;
  const ushort_t* xslk = xs + (p * 2) * (34 * 72) + n16 * 72 + q * 8;

#pragma unroll 1
  for (int kh = 0; kh < 3; ++kh) {
    bf16x8 a0[6], a1[6];
#pragma unroll
    for (int i = 0; i < 6; ++i) {  // i = kw2*2+cq, ks = kh*6+i
      a0[i] = *reinterpret_cast<const bf16x8*>(Ag0 + i * 32);
      a1[i] = *reinterpret_cast<const bf16x8*>(Ag1 + i * 32);
    }
#pragma unroll
    for (int pt = 0; pt < 4; ++pt) {
      int rloc = pt >> 1;
      int colb = (pt & 1) * 16;
#pragma unroll
      for (int kw2 = 0; kw2 < 3; ++kw2) {
#pragma unroll
        for (int cq = 0; cq < 2; ++cq) {
          bf16x8 bv = *reinterpret_cast<const bf16x8*>(
              xslk + (rloc * 34 + colb + kw2) * 72 + cq * 32);
          int i = kw2 * 2 + cq;
          acc[pt][0] = __builtin_amdgcn_mfma_f32_16x16x32_bf16(a0[i], bv, acc[pt][0], 0, 0, 0);
          acc[pt][1] = __builtin_amdgcn_mfma_f32_16x16x32_bf16(a1[i], bv, acc[pt][1], 0, 0, 0);
        }
      }
    }
    Ag0 += 192;            // 6 k-steps * 32 elems
    Ag1 += 192;
    xslk += 34 * 72;       // next kh row
  }

  f32x4 bias0 = *reinterpret_cast<const f32x4*>(bias + oh * 32 + q * 4);
  f32x4 bias1 = *reinterpret_cast<const f32x4*>(bias + oh * 32 + 16 + q * 4);

  // epilogue: per output row, stage [64 o][32 w] into LDS (stride 36), store 128-B runs
#pragma unroll
  for (int rr = 0; rr < 4; ++rr) {
    __syncthreads();  // buf free (also closes MFMA B-reads on rr==0)
    if ((rr >> 1) == p) {
      int ptb = (rr & 1) * 2;
#pragma unroll
      for (int cb = 0; cb < 2; ++cb) {
        int pt = ptb + cb;
        int w = cb * 16 + n16;
#pragma unroll
        for (int r = 0; r < 4; ++r) {
          buf[(oh * 32 + q * 4 + r) * 36 + w] = fmaxf(acc[pt][0][r] + bias0[r], 0.f);
          buf[(oh * 32 + 16 + q * 4 + r) * 36 + w] = fmaxf(acc[pt][1][r] + bias1[r], 0.f);
        }
      }
    }
    __syncthreads();
    float* op = out + ((size_t)(b * 64) * 128 + (h0 + rr)) * 128 + w0;
#pragma unroll
    for (int k = 0; k < 2; ++k) {
      int idx = tid + k * 256;   // 512 float4 = 64 o * 8 wq
      int o = idx >> 3;
      int wq = idx & 7;
      f32x4 v = *reinterpret_cast<f32x4*>(buf + o * 36 + wq * 4);
      *reinterpret_cast<f32x4*>(op + (size_t)o * 16384 + wq * 4) = v;
    }
  }
}

extern "C" void kernel_launch(void* const* d_in, const int* in_sizes, int n_in,
                              void* d_out, int out_size, void* d_ws, size_t ws_size,
                              hipStream_t stream) {
  const float* x       = (const float*)d_in[0];
  const float* ctx_w   = (const float*)d_in[1];
  const float* ctx_b   = (const float*)d_in[2];
  const float* kg_w    = (const float*)d_in[3];
  const float* kg_b    = (const float*)d_in[4];
  const float* gamma   = (const float*)d_in[5];
  const float* bias    = (const float*)d_in[6];
  const float* value_w = (const float*)d_in[7];
  float* out = (float*)d_out;

  float* part  = (float*)((char*)d_ws + WS_PART);
  ushort_t* xTp = (ushort_t*)((char*)d_ws + WS_XT);
  ushort_t* A  = (ushort_t*)((char*)d_ws + WS_A);

  k_trans<<<1040, 256, 0, stream>>>(x, xTp, part);
  k_gen<<<512, 256, 0, stream>>>(part, ctx_w, ctx_b, kg_w, kg_b, gamma, value_w, A);
  k_conv<<<1024, 256, 0, stream>>>(xTp, A, bias, out);
}